// Round 3
// baseline (302.669 us; speedup 1.0000x reference)
//
#include <hip/hip_runtime.h>

typedef __attribute__((ext_vector_type(8))) short bf16x8;
typedef __attribute__((ext_vector_type(4))) float f32x4;

#define HH 768   // hidden
#define EE 768   // embed
#define BB 32
#define SS 512
#define PP 76
#define KCAND 64
#define MM (BB * PP)  // 2432
#define VV 50257

#define CONV_BLOCKS 18847          // ceil(50257*768/8 / 256)
#define WT_BLOCKS 576
#define GATH_BLOCKS 304

// round-to-nearest-even fp32 -> bf16 bit pattern
__device__ inline unsigned short f2bf(float f) {
    unsigned int u = __float_as_uint(f);
    u += 0x7fffu + ((u >> 16) & 1u);
    return (unsigned short)(u >> 16);
}
__device__ inline float bf2f(short h) {
    return __uint_as_float(((unsigned int)(unsigned short)h) << 16);
}
__device__ inline float dot8(bf16x8 c, const float4 m0, const float4 m1) {
    return bf2f(c[0]) * m0.x + bf2f(c[1]) * m0.y + bf2f(c[2]) * m0.z + bf2f(c[3]) * m0.w
         + bf2f(c[4]) * m1.x + bf2f(c[5]) * m1.y + bf2f(c[6]) * m1.z + bf2f(c[7]) * m1.w;
}

// Pass 0 (fused, one dispatch):
//   blocks [0, CONV)             : emb fp32 -> embb bf16 (streaming)
//   blocks [CONV, CONV+WT)       : W transpose+convert -> Wt[e][h] bf16
//   blocks [CONV+WT, ...+GATH)   : gather masked rows -> Ag[m][k] bf16
__global__ __launch_bounds__(256) void prep_kernel(
    const float* __restrict__ W, unsigned short* __restrict__ Wt,
    const float* __restrict__ seq, const int* __restrict__ mpos,
    unsigned short* __restrict__ Ag,
    const float* __restrict__ emb, unsigned short* __restrict__ embb) {
    const int bid = blockIdx.x;
    if (bid < CONV_BLOCKS) {
        const size_t i8 = ((size_t)bid * 256 + threadIdx.x) * 8;
        if (i8 < (size_t)VV * EE) {
            const float4 a = *(const float4*)(emb + i8);
            const float4 b = *(const float4*)(emb + i8 + 4);
            unsigned short t[8];
            t[0] = f2bf(a.x); t[1] = f2bf(a.y); t[2] = f2bf(a.z); t[3] = f2bf(a.w);
            t[4] = f2bf(b.x); t[5] = f2bf(b.y); t[6] = f2bf(b.z); t[7] = f2bf(b.w);
            *(int4*)(embb + i8) = *(const int4*)t;
        }
    } else if (bid < CONV_BLOCKS + WT_BLOCKS) {
        __shared__ float tile[32][33];
        const int wb = bid - CONV_BLOCKS;
        const int h0 = (wb % 24) * 32, e0 = (wb / 24) * 32;
        const int c = threadIdx.x & 31, r = threadIdx.x >> 5;  // r: 0..7
#pragma unroll
        for (int rr = r; rr < 32; rr += 8)
            tile[rr][c] = W[(size_t)(h0 + rr) * EE + e0 + c];
        __syncthreads();
#pragma unroll
        for (int rr = r; rr < 32; rr += 8)
            Wt[(size_t)(e0 + rr) * HH + h0 + c] = f2bf(tile[c][rr]);
    } else {
        const int m0 = (bid - CONV_BLOCKS - WT_BLOCKS) * 8;
        const int t = threadIdx.x;
#pragma unroll
        for (int rr = 0; rr < 8; ++rr) {
            const int m = m0 + rr;
            const int b = m / PP, p = m - b * PP;
            const int ps = mpos[b * PP + p];
            const float* srow = seq + (size_t)(b * SS + ps) * HH;
            unsigned short* drow = Ag + (size_t)m * HH;
#pragma unroll
            for (int j = 0; j < 3; ++j) {
                const int idx = t + j * 256;
                drow[idx] = f2bf(srow[idx]);
            }
        }
    }
}

// Pass 1: lm_raw[m][e] = sum_h Ag[m][h] * Wt[e][h]  (both bf16, [row][k])
// Tile 64x64, BK=128, pure 16B staging copies, 2x2 waves of 32x32.
__global__ __launch_bounds__(256) void gemm_kernel(
    const unsigned short* __restrict__ Ag, const unsigned short* __restrict__ Wt,
    float* __restrict__ lm) {
    __shared__ unsigned short Alds[64][136];
    __shared__ unsigned short Blds[64][136];
    const int bm = blockIdx.y, bn = blockIdx.x;
    const int tid = threadIdx.x;
    const int sr = tid >> 4;
    const int sc = (tid & 15) * 8;
    const unsigned short* abase = Ag + (size_t)(bm * 64) * HH;
    const unsigned short* bbase = Wt + (size_t)(bn * 64) * HH;

    const int lane = tid & 63, wv = tid >> 6;
    const int wm = wv >> 1, wn = wv & 1;
    const int fr = lane & 15, fq = (lane >> 4) * 8;
    f32x4 acc[2][2] = {};

    for (int kk = 0; kk < HH; kk += 128) {
        __syncthreads();
#pragma unroll
        for (int rnd = 0; rnd < 4; ++rnd) {
            const int row = sr + rnd * 16;
            *(int4*)&Alds[row][sc] = *(const int4*)(abase + (size_t)row * HH + kk + sc);
            *(int4*)&Blds[row][sc] = *(const int4*)(bbase + (size_t)row * HH + kk + sc);
        }
        __syncthreads();
#pragma unroll
        for (int ks = 0; ks < 128; ks += 32) {
            bf16x8 af[2], bfr[2];
#pragma unroll
            for (int t = 0; t < 2; ++t)
                af[t] = *(const bf16x8*)&Alds[wm * 32 + t * 16 + fr][ks + fq];
#pragma unroll
            for (int t = 0; t < 2; ++t)
                bfr[t] = *(const bf16x8*)&Blds[wn * 32 + t * 16 + fr][ks + fq];
#pragma unroll
            for (int tm = 0; tm < 2; ++tm)
#pragma unroll
                for (int tn = 0; tn < 2; ++tn)
                    acc[tm][tn] = __builtin_amdgcn_mfma_f32_16x16x32_bf16(
                        af[tm], bfr[tn], acc[tm][tn], 0, 0, 0);
        }
    }
#pragma unroll
    for (int tm = 0; tm < 2; ++tm)
#pragma unroll
        for (int tn = 0; tn < 2; ++tn) {
            const int col = bn * 64 + wn * 32 + tn * 16 + (lane & 15);
            const int rbase = bm * 64 + wm * 32 + tm * 16 + (lane >> 4) * 4;
#pragma unroll
            for (int g = 0; g < 4; ++g)
                lm[(size_t)(rbase + g) * EE + col] = acc[tm][tn][g];
        }
}

// Pass 2: bias + LayerNorm (fused) + candidate dots against bf16 table.
// One block per (b,p). Candidate PAIRS per wave: 2 rows = 192 16B-chunks =
// exactly 3 chunks/lane (uniform, no divergence). lm chunks pre-swizzled
// into registers (M0/M1/M2) so the pair loop is 3 loads + 24 FMA + 1 select.
__global__ __launch_bounds__(256) void logits_kernel(
    const float* __restrict__ lm, const float* __restrict__ bias,
    const float* __restrict__ gamma, const float* __restrict__ beta,
    const int* __restrict__ cand, const unsigned short* __restrict__ embb,
    float* __restrict__ out) {
    __shared__ float4 rowv4[192];  // 768 floats
    __shared__ float reds[4], redq[4], stat[2];
    float* row = (float*)rowv4;
    const int bp = blockIdx.x;
    const int tid = threadIdx.x, lane = tid & 63, wv = tid >> 6;

    float s = 0.f, qq = 0.f;
    float v[3];
#pragma unroll
    for (int i = 0; i < 3; ++i) {
        const int idx = tid + i * 256;
        const float x = lm[(size_t)bp * EE + idx] + bias[idx];
        v[i] = x; s += x; qq += x * x;
    }
#pragma unroll
    for (int m = 32; m; m >>= 1) { s += __shfl_xor(s, m); qq += __shfl_xor(qq, m); }
    if (lane == 0) { reds[wv] = s; redq[wv] = qq; }
    __syncthreads();
    if (tid == 0) {
        const float S = reds[0] + reds[1] + reds[2] + reds[3];
        const float Q = redq[0] + redq[1] + redq[2] + redq[3];
        const float mu = S * (1.0f / 768.0f);
        const float var = Q * (1.0f / 768.0f) - mu * mu;
        stat[0] = mu; stat[1] = rsqrtf(var + 1e-12f);
    }
    __syncthreads();
    const float mu = stat[0], rstd = stat[1];
#pragma unroll
    for (int i = 0; i < 3; ++i) {
        const int idx = tid + i * 256;
        row[idx] = (v[i] - mu) * rstd * gamma[idx] + beta[idx];
    }
    __syncthreads();

    // lm chunks j, j+32, j+64 (chunk = 8 floats), pre-swizzled per half-wave:
    // lane<32: chunks map g0->L0, g1->L2, g2->L1 ; lane>=32: g0->L1, g1->L0, g2->L2
    const int j = lane & 31;
    const bool halflo = (lane < 32);
    const float4 A0 = rowv4[2 * j],        A1 = rowv4[2 * j + 1];
    const float4 B0 = rowv4[2 * (j + 32)], B1 = rowv4[2 * (j + 32) + 1];
    const float4 C0 = rowv4[2 * (j + 64)], C1 = rowv4[2 * (j + 64) + 1];
    const float4 M00 = halflo ? A0 : B0, M01 = halflo ? A1 : B1;
    const float4 M10 = halflo ? C0 : A0, M11 = halflo ? C1 : A1;
    const float4 M20 = halflo ? B0 : C0, M21 = halflo ? B1 : C1;

    const int kbase = wv * 16;
#pragma unroll
    for (int grp = 0; grp < 2; ++grp) {
        bf16x8 c[4][3];
#pragma unroll
        for (int pr = 0; pr < 4; ++pr) {
            const int kp = kbase + grp * 8 + pr * 2;
            const int ca = cand[bp * KCAND + kp];
            const int cb = cand[bp * KCAND + kp + 1];
            const unsigned short* rA = embb + (size_t)ca * EE;
            const unsigned short* rB = embb + (size_t)cb * EE;
            c[pr][0] = *(const bf16x8*)(rA + lane * 8);
            const unsigned short* p1 = halflo ? (rA + (lane + 64) * 8)
                                              : (rB + (lane - 32) * 8);
            c[pr][1] = *(const bf16x8*)p1;
            c[pr][2] = *(const bf16x8*)(rB + (lane + 32) * 8);
        }
#pragma unroll
        for (int pr = 0; pr < 4; ++pr) {
            const float d0 = dot8(c[pr][0], M00, M01);
            const float d1 = dot8(c[pr][1], M10, M11);
            const float d2 = dot8(c[pr][2], M20, M21);
            const float t = halflo ? d1 : 0.f;
            float sA = d0 + t;
            float sB = d2 + (d1 - t);
#pragma unroll
            for (int m = 32; m; m >>= 1) {
                sA += __shfl_xor(sA, m);
                sB += __shfl_xor(sB, m);
            }
            if (lane == 0) {
                const int kp = kbase + grp * 8 + pr * 2;
                out[bp * KCAND + kp] = sA;
                out[bp * KCAND + kp + 1] = sB;
            }
        }
    }
}

extern "C" void kernel_launch(void* const* d_in, const int* in_sizes, int n_in,
                              void* d_out, int out_size, void* d_ws, size_t ws_size,
                              hipStream_t stream) {
    const float* seq   = (const float*)d_in[0];
    const int*   mpos  = (const int*)d_in[1];
    const int*   cand  = (const int*)d_in[2];
    const float* emb   = (const float*)d_in[3];
    const float* W     = (const float*)d_in[4];
    const float* bias  = (const float*)d_in[5];
    const float* gamma = (const float*)d_in[6];
    const float* beta  = (const float*)d_in[7];
    float* out = (float*)d_out;

    // ws: Wt bf16 1,179,648 | Ag bf16 3,735,552 | lm fp32 7,471,104 | embb bf16 77,194,752
    unsigned short* Wt = (unsigned short*)d_ws;
    unsigned short* Ag = (unsigned short*)((char*)d_ws + 1179648);
    float* lm          = (float*)((char*)d_ws + 4915200);
    unsigned short* embb = (unsigned short*)((char*)d_ws + 12386304);

    prep_kernel<<<CONV_BLOCKS + WT_BLOCKS + GATH_BLOCKS, 256, 0, stream>>>(
        W, Wt, seq, mpos, Ag, emb, embb);
    gemm_kernel<<<dim3(12, 38), 256, 0, stream>>>(Ag, Wt, lm);
    logits_kernel<<<MM, 256, 0, stream>>>(lm, bias, gamma, beta, cand, embb, out);
}